// Round 6
// baseline (213.149 us; speedup 1.0000x reference)
//
#include <hip/hip_runtime.h>
#include <hip/hip_cooperative_groups.h>

namespace cg = cooperative_groups;

#define N_NODES  100000
#define N_EDGES  1600000
#define N_GRAPHS 256
#define F        64

// ---------------------------------------------------------------------------
// R23. R5's cooperative kernel failed with absmax == max|ref| ~= 14.25 ->
// output was still memset-zero -> the cooperative ENQUEUE failed (unchecked
// return), kernel never ran. Phase logic re-audited clean. This round keeps
// the single-kernel design but gates it: host-side occupancy + coop-support
// queries (capture-safe), checked launch, and a full 5-kernel fallback path
// sharing the exact same __device__ phase bodies. Evidence carried forward:
//  - R0/R4: gather body 80us proven; total-minus-bodies ~60-70us across 4-6
//    dispatches -> per-dispatch overhead ~10-14us is the remaining target.
//  - R3: random 4B global writes cost a 64B line each -> all scatter stays
//    LDS-staged / block-local.
//  - R1: never cap VGPR below need ((256,8) spilled); (256,4)=128 cap is safe
//    (gather needs ~60).
// ---------------------------------------------------------------------------

#define GRID     1024
#define BLK      256

#define NBUCK    196          // buckets of 512 nodes (dst >> 9)
#define BCAP     9216         // mean 8192, sigma ~90 -> +11 sigma
#define BSTRIDE  16           // balloc: one counter per 64B line

#define EPB      1563         // ceil(N_EDGES / GRID)
#define REPT     7            // ceil(EPB / BLK)

#define CAST_ELEMS (N_NODES * F / 4)   // 1,600,000 float4
#define NODES_PER_WAVE 25              // 4096 waves x 25 = 102400 >= N_NODES

__device__ __forceinline__ unsigned short f2bf(float f) {
    unsigned int u = __float_as_uint(f);
    u += 0x7FFFu + ((u >> 16) & 1u);
    return (unsigned short)(u >> 16);
}
__device__ __forceinline__ float bfl(unsigned int u) { return __uint_as_float(u << 16); }
__device__ __forceinline__ float bfh(unsigned int u) { return __uint_as_float(u & 0xFFFF0000u); }

struct SharedBin {
    int hist[NBUCK]; int roffs[NBUCK]; int bbase[NBUCK]; int curs[NBUCK];
    int wsum[8];
    unsigned int   stage[EPB];
    unsigned short bstage[EPB];
};                                     // ~12.6 KB
struct SharedSort { int hist[512]; int curs[512]; int wsum[8]; };   // ~4.1 KB
union SharedU { SharedBin bin; SharedSort sort; };

// ---------------- phase bodies (shared by fused + split kernels) ----------------

__device__ __forceinline__ void phase_zero(int bid, int tid,
        float* out, float* denom, int* balloc) {
    int g0 = bid * BLK + tid;
    if (g0 < N_GRAPHS * F) out[g0] = 0.f;
    if (g0 < N_GRAPHS) denom[g0] = 0.f;
    if (g0 < NBUCK) balloc[g0 * BSTRIDE] = 0;
}

__device__ __forceinline__ void phase_bin(int bid, int tid,
        const int* __restrict__ src, const int* __restrict__ dst,
        unsigned int* __restrict__ pairs, int* __restrict__ balloc,
        SharedBin& s) {
    int lane = tid & 63, wv = tid >> 6;
    int base = bid * EPB;
    int m    = min(EPB, N_EDGES - base);

    for (int k = tid; k < NBUCK; k += BLK) s.hist[k] = 0;
    __syncthreads();

    int de[REPT], se[REPT];
    #pragma unroll
    for (int r = 0; r < REPT; ++r) {
        int e = tid + r * BLK;
        if (e < m) {
            de[r] = dst[base + e];
            se[r] = src[base + e];
            atomicAdd(&s.hist[de[r] >> 9], 1);
        } else { de[r] = -1; se[r] = 0; }
    }
    __syncthreads();

    int cnt = (tid < NBUCK) ? s.hist[tid] : 0;
    int v = cnt;
    #pragma unroll
    for (int o = 1; o < 64; o <<= 1) {
        int u = __shfl_up(v, o, 64);
        if (lane >= o) v += u;
    }
    if (lane == 63) s.wsum[wv] = v;
    __syncthreads();
    if (tid < 4) {
        int sv = s.wsum[tid];
        int u = __shfl_up(sv, 1, 64); if (tid >= 1) sv += u;
        u     = __shfl_up(sv, 2, 64); if (tid >= 2) sv += u;
        s.wsum[tid] = sv;
    }
    __syncthreads();
    if (wv > 0) v += s.wsum[wv - 1];
    if (tid < NBUCK) {
        int excl = v - cnt;
        s.roffs[tid] = excl;
        s.curs[tid]  = excl;
        s.bbase[tid] = tid * BCAP + atomicAdd(&balloc[tid * BSTRIDE], cnt);
    }
    __syncthreads();

    #pragma unroll
    for (int r = 0; r < REPT; ++r) {
        if (de[r] >= 0) {
            int bk  = de[r] >> 9;
            int pos = atomicAdd(&s.curs[bk], 1);
            s.stage[pos]  = ((unsigned)(de[r] & 511) << 17) | (unsigned)se[r];
            s.bstage[pos] = (unsigned short)bk;
        }
    }
    __syncthreads();
    for (int e = tid; e < m; e += BLK) {
        int bk = s.bstage[e];
        pairs[s.bbase[bk] + (e - s.roffs[bk])] = s.stage[e];
    }
}

__device__ __forceinline__ void phase_sortcast(int bid, int tid,
        const float* __restrict__ x, unsigned short* __restrict__ xh,
        const unsigned int* __restrict__ pairs, int* __restrict__ eidx,
        int* __restrict__ nbeg, int* __restrict__ nend,
        const int* __restrict__ balloc, SharedSort& s) {
    int lane = tid & 63, wv = tid >> 6;
    if (bid < NBUCK) {
        int E     = balloc[bid * BSTRIDE];
        int base  = bid * BCAP;
        int node0 = bid << 9;
        int nn    = min(512, N_NODES - node0);

        s.hist[tid] = 0; s.hist[tid + 256] = 0;
        __syncthreads();
        for (int i = tid; i < E; i += BLK)
            atomicAdd(&s.hist[pairs[base + i] >> 17], 1);
        __syncthreads();

        int c0 = s.hist[tid];
        int v0 = c0;
        #pragma unroll
        for (int o = 1; o < 64; o <<= 1) { int u = __shfl_up(v0, o, 64); if (lane >= o) v0 += u; }
        if (lane == 63) s.wsum[wv] = v0;
        __syncthreads();
        if (tid < 4) {
            int sv = s.wsum[tid];
            int u = __shfl_up(sv, 1, 64); if (tid >= 1) sv += u;
            u     = __shfl_up(sv, 2, 64); if (tid >= 2) sv += u;
            s.wsum[tid] = sv;
        }
        __syncthreads();
        if (wv > 0) v0 += s.wsum[wv - 1];
        int total0 = s.wsum[3];

        int c1 = s.hist[tid + 256];
        int v1 = c1;
        #pragma unroll
        for (int o = 1; o < 64; o <<= 1) { int u = __shfl_up(v1, o, 64); if (lane >= o) v1 += u; }
        if (lane == 63) s.wsum[4 + wv] = v1;
        __syncthreads();
        if (tid < 4) {
            int sv = s.wsum[4 + tid];
            int u = __shfl_up(sv, 1, 64); if (tid >= 1) sv += u;
            u     = __shfl_up(sv, 2, 64); if (tid >= 2) sv += u;
            s.wsum[4 + tid] = sv;
        }
        __syncthreads();
        if (wv > 0) v1 += s.wsum[4 + wv - 1];
        v1 += total0;

        int e0 = v0 - c0, e1 = v1 - c1;
        s.curs[tid] = e0; s.curs[tid + 256] = e1;
        if (tid < nn)       { nbeg[node0 + tid] = base + e0;
                              nend[node0 + tid] = base + e0 + c0; }
        if (tid + 256 < nn) { nbeg[node0 + tid + 256] = base + e1;
                              nend[node0 + tid + 256] = base + e1 + c1; }
        __syncthreads();

        // scatter confined to this block's own 36KB region: lines merge in L2
        for (int i = tid; i < E; i += BLK) {
            unsigned int p = pairs[base + i];
            int pos = atomicAdd(&s.curs[p >> 17], 1);
            eidx[base + pos] = (int)(p & 0x1FFFFu);
        }
    } else {
        int i0      = (bid - NBUCK) * BLK + tid;
        int cstride = (GRID - NBUCK) * BLK;
        for (int i = i0; i < CAST_ELEMS; i += cstride) {
            float4 v4 = ((const float4*)x)[i];
            ushort4 o;
            o.x = f2bf(v4.x); o.y = f2bf(v4.y); o.z = f2bf(v4.z); o.w = f2bf(v4.w);
            ((ushort4*)xh)[i] = o;
        }
    }
}

__device__ __forceinline__ void phase_gather(int bid, int tid,
        const unsigned short* __restrict__ xh,
        const int* __restrict__ nbeg, const int* __restrict__ nend,
        const int* __restrict__ eidx, const int* __restrict__ batch,
        const float* __restrict__ Wg, const float* __restrict__ bg,
        const float* __restrict__ Wa, const float* __restrict__ ba,
        float* __restrict__ out, float* __restrict__ denom) {
    int lane = tid & 63;
    int grp  = lane >> 3;
    int c    = lane & 7;
    int waveId = bid * 4 + (tid >> 6);
    int n0 = waveId * NODES_PER_WAVE;
    if (n0 >= N_NODES) return;           // guarded: fused caller syncs OUTSIDE
    int nEnd = min(n0 + NODES_PER_WAVE, N_NODES);

    float wcol[F];
    #pragma unroll
    for (int k = 0; k < F; ++k) wcol[k] = Wg[k * F + lane];
    float bgl = bg[lane];
    float wal = Wa[lane];
    float ba0 = ba[0];

    const uint4* xh4 = (const uint4*)xh;

    int   cur_g = batch[n0];
    float accw  = 0.f;
    float denw  = 0.f;

    int pb = nbeg[n0];
    int pe = nend[n0];
    int sl_cur = (pb + lane < pe) ? eidx[pb + lane] : 0;

    for (int n = n0; n < nEnd; ++n) {
        int start = pb, end = pe;
        int sl    = sl_cur;
        if (n + 1 < nEnd) {
            pb = nbeg[n + 1];
            pe = nend[n + 1];
            sl_cur = (pb + lane < pe) ? eidx[pb + lane] : 0;
        }

        float a0=0.f,a1=0.f,a2=0.f,a3=0.f,a4=0.f,a5=0.f,a6=0.f,a7=0.f;
        {
            int jmax = end - start; if (jmax > 64) jmax = 64;
            for (int j = 0; j < jmax; j += 8) {
                int el = j + grp;
                int sidx = __shfl(sl, el, 64);
                if (el < jmax) {
                    uint4 v = xh4[sidx * 8 + c];
                    a0 += bfl(v.x); a1 += bfh(v.x);
                    a2 += bfl(v.y); a3 += bfh(v.y);
                    a4 += bfl(v.z); a5 += bfh(v.z);
                    a6 += bfl(v.w); a7 += bfh(v.w);
                }
            }
        }
        for (int base2 = start + 64; base2 < end; base2 += 64) {
            int jmax = end - base2; if (jmax > 64) jmax = 64;
            int sl2 = (base2 + lane < end) ? eidx[base2 + lane] : 0;
            for (int j = 0; j < jmax; j += 8) {
                int el = j + grp;
                int sidx = __shfl(sl2, el, 64);
                if (el < jmax) {
                    uint4 v = xh4[sidx * 8 + c];
                    a0 += bfl(v.x); a1 += bfh(v.x);
                    a2 += bfl(v.y); a3 += bfh(v.y);
                    a4 += bfl(v.z); a5 += bfh(v.z);
                    a6 += bfl(v.w); a7 += bfh(v.w);
                }
            }
        }
        #pragma unroll
        for (int o = 8; o <= 32; o <<= 1) {
            a0 += __shfl_xor(a0, o, 64); a1 += __shfl_xor(a1, o, 64);
            a2 += __shfl_xor(a2, o, 64); a3 += __shfl_xor(a3, o, 64);
            a4 += __shfl_xor(a4, o, 64); a5 += __shfl_xor(a5, o, 64);
            a6 += __shfl_xor(a6, o, 64); a7 += __shfl_xor(a7, o, 64);
        }
        {
            uint4 v = xh4[n * 8 + c];   // self row
            a0 += bfl(v.x); a1 += bfh(v.x);
            a2 += bfl(v.y); a3 += bfh(v.y);
            a4 += bfl(v.z); a5 += bfh(v.z);
            a6 += bfl(v.w); a7 += bfh(v.w);
        }

        float re[8] = {a0,a1,a2,a3,a4,a5,a6,a7};
        float q0=0.f,q1=0.f,q2=0.f,q3=0.f,q4=0.f,q5=0.f,q6=0.f,q7=0.f;
        #pragma unroll
        for (int k = 0; k < F; k += 8) {
            int ln = k >> 3;
            q0 += __int_as_float(__builtin_amdgcn_readlane(__float_as_int(re[0]), ln)) * wcol[k + 0];
            q1 += __int_as_float(__builtin_amdgcn_readlane(__float_as_int(re[1]), ln)) * wcol[k + 1];
            q2 += __int_as_float(__builtin_amdgcn_readlane(__float_as_int(re[2]), ln)) * wcol[k + 2];
            q3 += __int_as_float(__builtin_amdgcn_readlane(__float_as_int(re[3]), ln)) * wcol[k + 3];
            q4 += __int_as_float(__builtin_amdgcn_readlane(__float_as_int(re[4]), ln)) * wcol[k + 4];
            q5 += __int_as_float(__builtin_amdgcn_readlane(__float_as_int(re[5]), ln)) * wcol[k + 5];
            q6 += __int_as_float(__builtin_amdgcn_readlane(__float_as_int(re[6]), ln)) * wcol[k + 6];
            q7 += __int_as_float(__builtin_amdgcn_readlane(__float_as_int(re[7]), ln)) * wcol[k + 7];
        }
        float hv = ((q0 + q1) + (q2 + q3)) + ((q4 + q5) + (q6 + q7)) + bgl;
        hv = hv > 0.f ? hv : 0.f;

        float p = hv * wal;
        #pragma unroll
        for (int o = 32; o > 0; o >>= 1)
            p += __shfl_down(p, o, 64);
        float sc = __int_as_float(__builtin_amdgcn_readlane(__float_as_int(p), 0)) + ba0;
        float e = __expf(sc);   // unshifted: softmax ratio is shift-invariant

        int g = batch[n];       // wave-uniform
        if (g != cur_g) {
            atomicAdd(&out[cur_g * F + lane], accw);
            if (lane == 0) atomicAdd(&denom[cur_g], denw);
            accw = 0.f; denw = 0.f; cur_g = g;
        }
        accw += e * hv;
        denw += e;
    }
    atomicAdd(&out[cur_g * F + lane], accw);
    if (lane == 0) atomicAdd(&denom[cur_g], denw);
}

__device__ __forceinline__ void phase_fin(int bid, int tid,
        float* out, const float* denom) {
    int g0 = bid * BLK + tid;
    if (g0 < N_GRAPHS * F) {
        float d = denom[g0 >> 6];
        out[g0] = (d > 0.f) ? out[g0] / d : 0.f;
    }
}

// ---------------- fused cooperative kernel ----------------
__global__ __launch_bounds__(BLK, 4) void fused_kernel(
        const float* __restrict__ x,
        const int* __restrict__ src, const int* __restrict__ dst,
        const int* __restrict__ batch,
        const float* __restrict__ Wg, const float* __restrict__ bg,
        const float* __restrict__ Wa, const float* __restrict__ ba,
        float* __restrict__ out,
        unsigned short* __restrict__ xh,
        unsigned int* __restrict__ pairs, int* __restrict__ eidx,
        int* __restrict__ nbeg, int* __restrict__ nend,
        int* __restrict__ balloc, float* __restrict__ denom) {
    cg::grid_group grid = cg::this_grid();
    __shared__ SharedU sh;
    int tid = threadIdx.x, bid = blockIdx.x;

    phase_zero(bid, tid, out, denom, balloc);
    __threadfence(); grid.sync(); __threadfence();

    phase_bin(bid, tid, src, dst, pairs, balloc, sh.bin);
    __threadfence(); grid.sync(); __threadfence();

    phase_sortcast(bid, tid, x, xh, pairs, eidx, nbeg, nend, balloc, sh.sort);
    __threadfence(); grid.sync(); __threadfence();

    phase_gather(bid, tid, xh, nbeg, nend, eidx, batch, Wg, bg, Wa, ba, out, denom);
    __threadfence(); grid.sync(); __threadfence();

    phase_fin(bid, tid, out, denom);
}

// ---------------- split fallback kernels (identical bodies) ----------------
__global__ __launch_bounds__(BLK) void k_zero(float* out, float* denom, int* balloc) {
    phase_zero(blockIdx.x, threadIdx.x, out, denom, balloc);
}
__global__ __launch_bounds__(BLK) void k_bin(const int* src, const int* dst,
        unsigned int* pairs, int* balloc) {
    __shared__ SharedBin s;
    phase_bin(blockIdx.x, threadIdx.x, src, dst, pairs, balloc, s);
}
__global__ __launch_bounds__(BLK) void k_sortcast(const float* x, unsigned short* xh,
        const unsigned int* pairs, int* eidx, int* nbeg, int* nend, const int* balloc) {
    __shared__ SharedSort s;
    phase_sortcast(blockIdx.x, threadIdx.x, x, xh, pairs, eidx, nbeg, nend, balloc, s);
}
__global__ __launch_bounds__(BLK) void k_gather(const unsigned short* xh,
        const int* nbeg, const int* nend, const int* eidx, const int* batch,
        const float* Wg, const float* bg, const float* Wa, const float* ba,
        float* out, float* denom) {
    phase_gather(blockIdx.x, threadIdx.x, xh, nbeg, nend, eidx, batch,
                 Wg, bg, Wa, ba, out, denom);
}
__global__ __launch_bounds__(BLK) void k_fin(float* out, const float* denom) {
    phase_fin(blockIdx.x, threadIdx.x, out, denom);
}

extern "C" void kernel_launch(void* const* d_in, const int* in_sizes, int n_in,
                              void* d_out, int out_size, void* d_ws, size_t ws_size,
                              hipStream_t stream) {
    const float* x     = (const float*)d_in[0];
    const int*   ei    = (const int*)d_in[1];   // [2, N_EDGES]
    const int*   batch = (const int*)d_in[2];   // [N_NODES]
    const float* Wg    = (const float*)d_in[3];
    const float* bg    = (const float*)d_in[4];
    const float* Wa    = (const float*)d_in[5];
    const float* ba    = (const float*)d_in[6];
    float* out = (float*)d_out;

    const int* src = ei;
    const int* dst = ei + N_EDGES;

    // workspace layout (bytes), ~28.07 MB
    char* ws = (char*)d_ws;
    unsigned short* xh     = (unsigned short*)(ws);            // 12,800,000
    unsigned int*   pairs  = (unsigned int*)(ws + 12800000);   //  7,225,344
    int*            eidx   = (int*)(ws + 20025344);            //  7,225,344
    int*            nbeg   = (int*)(ws + 27250688);            //    400,000
    int*            nend   = (int*)(ws + 27652096);            //    400,000
    int*            balloc = (int*)(ws + 28053504);            //     12,544
    float*          denom  = (float*)(ws + 28066048);          //      1,024

    // one-time host-side gate (capture-safe queries only)
    static int s_path = -1;   // 1 = cooperative, 0 = split
    if (s_path < 0) {
        int dev = 0; hipGetDevice(&dev);
        int coop = 0;
        hipDeviceGetAttribute(&coop, hipDeviceAttributeCooperativeLaunch, dev);
        int ncu = 0;
        hipDeviceGetAttribute(&ncu, hipDeviceAttributeMultiprocessorCount, dev);
        int maxB = 0;
        hipOccupancyMaxActiveBlocksPerMultiprocessor(&maxB, fused_kernel, BLK, 0);
        s_path = (coop != 0 && (long)maxB * (long)ncu >= GRID) ? 1 : 0;
    }

    if (s_path == 1) {
        void* kargs[] = {
            (void*)&x, (void*)&src, (void*)&dst, (void*)&batch,
            (void*)&Wg, (void*)&bg, (void*)&Wa, (void*)&ba,
            (void*)&out, (void*)&xh, (void*)&pairs, (void*)&eidx,
            (void*)&nbeg, (void*)&nend, (void*)&balloc, (void*)&denom
        };
        hipError_t err = hipLaunchCooperativeKernel(fused_kernel, dim3(GRID),
                                                    dim3(BLK), kargs, 0, stream);
        if (err != hipSuccess) s_path = 0;   // fall through to split path
    }
    if (s_path == 0) {
        k_zero    <<<64,   BLK, 0, stream>>>(out, denom, balloc);
        k_bin     <<<GRID, BLK, 0, stream>>>(src, dst, pairs, balloc);
        k_sortcast<<<GRID, BLK, 0, stream>>>(x, xh, pairs, eidx, nbeg, nend, balloc);
        k_gather  <<<GRID, BLK, 0, stream>>>(xh, nbeg, nend, eidx, batch,
                                             Wg, bg, Wa, ba, out, denom);
        k_fin     <<<64,   BLK, 0, stream>>>(out, denom);
    }
}